// Round 1
// baseline (387.405 us; speedup 1.0000x reference)
//
#include <hip/hip_runtime.h>
#include <hip/hip_fp16.h>

// MultiHeadAttention with softmax over the HEADS axis (faithful quirk).
// Pipeline: cvt->f16, 3 proj GEMMs (MFMA, global_load_lds staging),
// pass A: inverse head-softmax denominator IDn[i,j] = 1/sum_h exp(s_h*scale),
// pass B: per-head ctx = (exp(s_h*scale)*IDn) @ V_h  (scores recomputed
// bit-identically), final output GEMM fp32.

typedef _Float16 f16;
typedef _Float16 f16x4 __attribute__((ext_vector_type(4)));
typedef _Float16 f16x8 __attribute__((ext_vector_type(8)));
typedef float    f32x4 __attribute__((ext_vector_type(4)));

#define S_LEN 2048
#define DIM   1024
#define NH    16
#define DK    64
#define SCALE 0.125f

#define MFMA(a, b, c) __builtin_amdgcn_mfma_f32_16x16x32_f16(a, b, c, 0, 0, 0)

typedef __attribute__((address_space(1))) void g_void;
typedef __attribute__((address_space(3))) void l_void;

static __device__ __forceinline__ void gload_lds16(const void* g, void* l) {
  // async global->LDS DMA, 16B per lane; LDS dst = wave-uniform base + lane*16
  __builtin_amdgcn_global_load_lds((g_void*)g, (l_void*)l, 16, 0, 0);
}

// ---------------------------------------------------------------- cvt fp32->f16
__global__ __launch_bounds__(256) void cvt_f32_f16(const float* __restrict__ src,
                                                   f16* __restrict__ dst, int n4) {
  int i = blockIdx.x * 256 + threadIdx.x;
  if (i < n4) {
    float4 v = ((const float4*)src)[i];
    f16x4 o = {(f16)v.x, (f16)v.y, (f16)v.z, (f16)v.w};
    ((f16x4*)dst)[i] = o;
  }
}

// ---------------------------------------------------------------- GEMM: C = X @ W^T + bias
// X: (M,K) f16 row-major; W: (N,K) f16 row-major. 128x128 tile, 4 waves, each 64x64.
// MODE 0: f16 out (M,N); MODE 1: f16 out transposed (N,M); MODE 2: fp32 out (M,N)
template <int MODE>
__global__ __launch_bounds__(256) void gemm_xwt(const f16* __restrict__ X,
                                                const f16* __restrict__ W,
                                                const float* __restrict__ bias,
                                                f16* __restrict__ outh,
                                                float* __restrict__ outf,
                                                int M, int N, int K) {
  constexpr int BM = 128, BN = 128, BK = 32;
  __shared__ __align__(16) f16 As[BM * BK];
  __shared__ __align__(16) f16 Bs[BN * BK];

  const int tid = threadIdx.x;
  const int wv = tid >> 6;
  const int lane = tid & 63;
  const int qd = lane >> 4;    // quad 0..3
  const int l16 = lane & 15;
  const int bm = blockIdx.y * BM;
  const int bn = blockIdx.x * BN;
  const int wm = (wv & 1) * 64;
  const int wn = (wv >> 1) * 64;

  f32x4 acc[4][4];
#pragma unroll
  for (int a = 0; a < 4; a++)
#pragma unroll
    for (int b = 0; b < 4; b++) acc[a][b] = (f32x4){0.f, 0.f, 0.f, 0.f};

  // staging: wave wv owns rows [wv*32, wv*32+32) of both tiles, 2 instrs of 16 rows
  const int srow = wv * 32 + (lane >> 2);
  const int skcol = (lane & 3) * 8;
  const f16* gA = X + (size_t)(bm + srow) * K + skcol;
  const f16* gB = W + (size_t)(bn + srow) * K + skcol;
  f16* lA = &As[(wv * 32) * BK];
  f16* lB = &Bs[(wv * 32) * BK];

  for (int kt = 0; kt < K; kt += BK) {
    gload_lds16(gA, lA);
    gload_lds16(gA + 16 * K, lA + 16 * BK);
    gload_lds16(gB, lB);
    gload_lds16(gB + 16 * K, lB + 16 * BK);
    gA += BK;
    gB += BK;
    __syncthreads();  // drains vmcnt -> LDS tiles visible

    f16x8 af[4], bf[4];
#pragma unroll
    for (int mi = 0; mi < 4; mi++)
      af[mi] = *(const f16x8*)&As[(wm + mi * 16 + l16) * BK + qd * 8];
#pragma unroll
    for (int ni = 0; ni < 4; ni++)
      bf[ni] = *(const f16x8*)&Bs[(wn + ni * 16 + l16) * BK + qd * 8];
#pragma unroll
    for (int mi = 0; mi < 4; mi++)
#pragma unroll
      for (int ni = 0; ni < 4; ni++)
        acc[mi][ni] = MFMA(af[mi], bf[ni], acc[mi][ni]);
    __syncthreads();
  }

#pragma unroll
  for (int mi = 0; mi < 4; mi++) {
#pragma unroll
    for (int ni = 0; ni < 4; ni++) {
      const int gm = bm + wm + mi * 16 + qd * 4;
      const int gn = bn + wn + ni * 16 + l16;
      const float bs = bias[gn];
      if (MODE == 1) {
        f16x4 o = {(f16)(acc[mi][ni][0] + bs), (f16)(acc[mi][ni][1] + bs),
                   (f16)(acc[mi][ni][2] + bs), (f16)(acc[mi][ni][3] + bs)};
        *(f16x4*)&outh[(size_t)gn * M + gm] = o;  // gm % 4 == 0 -> 8B aligned
      } else {
#pragma unroll
        for (int r = 0; r < 4; r++) {
          float vv = acc[mi][ni][r] + bs;
          if (MODE == 0)
            outh[(size_t)(gm + r) * N + gn] = (f16)vv;
          else
            outf[(size_t)(gm + r) * N + gn] = vv;
        }
      }
    }
  }
}

// ---------------------------------------------------------------- pass A: IDn = 1/sum_h exp
// block = 4 waves (2x2), each wave a 32x32 (i,j) tile. All-head scores land at
// identical (lane,reg) positions -> head softmax is a per-lane register reduction.
__global__ __launch_bounds__(256) void attn_denom(const f16* __restrict__ Qp,
                                                  const f16* __restrict__ Kp,
                                                  f16* __restrict__ IDn) {
  const int tid = threadIdx.x;
  const int wv = tid >> 6;
  const int lane = tid & 63;
  const int qd = lane >> 4;
  const int l16 = lane & 15;
  const int ib = blockIdx.y * 64 + (wv & 1) * 32;
  const int jb = blockIdx.x * 64 + (wv >> 1) * 32;

  float dsum[2][2][4];
#pragma unroll
  for (int mi = 0; mi < 2; mi++)
#pragma unroll
    for (int ni = 0; ni < 2; ni++)
#pragma unroll
      for (int r = 0; r < 4; r++) dsum[mi][ni][r] = 0.f;

  for (int h = 0; h < NH; h++) {
    f16x8 aq[2][2], bk[2][2];
#pragma unroll
    for (int mi = 0; mi < 2; mi++)
#pragma unroll
      for (int kk = 0; kk < 2; kk++)
        aq[mi][kk] = *(const f16x8*)(Qp + (size_t)(ib + mi * 16 + l16) * DIM +
                                     h * DK + kk * 32 + qd * 8);
#pragma unroll
    for (int ni = 0; ni < 2; ni++)
#pragma unroll
      for (int kk = 0; kk < 2; kk++)
        bk[ni][kk] = *(const f16x8*)(Kp + (size_t)(jb + ni * 16 + l16) * DIM +
                                     h * DK + kk * 32 + qd * 8);
#pragma unroll
    for (int mi = 0; mi < 2; mi++)
#pragma unroll
      for (int ni = 0; ni < 2; ni++) {
        f32x4 s = {0.f, 0.f, 0.f, 0.f};
        s = MFMA(aq[mi][0], bk[ni][0], s);  // same order as pass B -> bit-identical
        s = MFMA(aq[mi][1], bk[ni][1], s);
#pragma unroll
        for (int r = 0; r < 4; r++) dsum[mi][ni][r] += __expf(s[r] * SCALE);
      }
  }
#pragma unroll
  for (int mi = 0; mi < 2; mi++)
#pragma unroll
    for (int ni = 0; ni < 2; ni++)
#pragma unroll
      for (int r = 0; r < 4; r++) {
        const int gi = ib + mi * 16 + qd * 4 + r;
        const int gj = jb + ni * 16 + l16;
        IDn[(size_t)gi * S_LEN + gj] = (f16)(1.f / dsum[mi][ni][r]);
      }
}

// ---------------------------------------------------------------- pass B: ctx per head
// grid (S/64, NH); each wave: one 16-row Q tile of one head, streams j in 32-chunks.
__global__ __launch_bounds__(256) void attn_ctx(const f16* __restrict__ Qp,
                                                const f16* __restrict__ Kp,
                                                const f16* __restrict__ Vt,
                                                const f16* __restrict__ IDn,
                                                f16* __restrict__ Ct) {
  __shared__ __align__(16) f16 Plds[4][16 * 32];  // wave-private P scratch
  const int tid = threadIdx.x;
  const int wv = tid >> 6;
  const int lane = tid & 63;
  const int qd = lane >> 4;
  const int l16 = lane & 15;
  const int h = blockIdx.y;
  const int ib = blockIdx.x * 64 + wv * 16;
  f16* pl = Plds[wv];

  f16x8 aq[2];
#pragma unroll
  for (int kk = 0; kk < 2; kk++)
    aq[kk] = *(const f16x8*)(Qp + (size_t)(ib + l16) * DIM + h * DK + kk * 32 + qd * 8);

  f32x4 cacc[4];
#pragma unroll
  for (int nd = 0; nd < 4; nd++) cacc[nd] = (f32x4){0.f, 0.f, 0.f, 0.f};

  for (int j0 = 0; j0 < S_LEN; j0 += 32) {
#pragma unroll
    for (int ni = 0; ni < 2; ni++) {
      f16x8 bk0 = *(const f16x8*)(Kp + (size_t)(j0 + ni * 16 + l16) * DIM + h * DK + qd * 8);
      f16x8 bk1 = *(const f16x8*)(Kp + (size_t)(j0 + ni * 16 + l16) * DIM + h * DK + 32 + qd * 8);
      f32x4 s = {0.f, 0.f, 0.f, 0.f};
      s = MFMA(aq[0], bk0, s);  // same accumulation order as pass A
      s = MFMA(aq[1], bk1, s);
#pragma unroll
      for (int r = 0; r < 4; r++) {
        const int gi = ib + qd * 4 + r;
        const int gj = j0 + ni * 16 + l16;
        float p = __expf(s[r] * SCALE) * (float)IDn[(size_t)gi * S_LEN + gj];
        pl[(qd * 4 + r) * 32 + ni * 16 + l16] = (f16)p;  // C-layout -> A-layout via LDS
      }
    }
    f16x8 ap = *(const f16x8*)&pl[l16 * 32 + qd * 8];  // wave-private: no barrier
#pragma unroll
    for (int nd = 0; nd < 4; nd++) {
      f16x8 bv = *(const f16x8*)(Vt + (size_t)(h * DK + nd * 16 + l16) * S_LEN + j0 + qd * 8);
      cacc[nd] = MFMA(ap, bv, cacc[nd]);
    }
  }
#pragma unroll
  for (int nd = 0; nd < 4; nd++)
#pragma unroll
    for (int r = 0; r < 4; r++)
      Ct[(size_t)(ib + qd * 4 + r) * DIM + h * DK + nd * 16 + l16] = (f16)cacc[nd][r];
}

// ---------------------------------------------------------------- launcher
extern "C" void kernel_launch(void* const* d_in, const int* in_sizes, int n_in,
                              void* d_out, int out_size, void* d_ws, size_t ws_size,
                              hipStream_t stream) {
  const float* q  = (const float*)d_in[0];
  const float* k  = (const float*)d_in[1];
  const float* v  = (const float*)d_in[2];
  const float* Wq = (const float*)d_in[3];
  const float* bq = (const float*)d_in[4];
  const float* Wk = (const float*)d_in[5];
  const float* bk = (const float*)d_in[6];
  const float* Wv = (const float*)d_in[7];
  const float* bv = (const float*)d_in[8];
  const float* Wo = (const float*)d_in[9];
  const float* bo = (const float*)d_in[10];
  float* out = (float*)d_out;

  // ws layout (f16), 32 MB total. IDn aliases qh+kh (dead after proj GEMMs),
  // Ct aliases vh (dead after V proj) -- stream-ordered, safe.
  f16* w = (f16*)d_ws;
  f16* qh  = w;                       // S*DIM
  f16* kh  = qh + (size_t)S_LEN * DIM;
  f16* vh  = kh + (size_t)S_LEN * DIM;
  f16* wqh = vh + (size_t)S_LEN * DIM;  // DIM*DIM
  f16* wkh = wqh + (size_t)DIM * DIM;
  f16* wvh = wkh + (size_t)DIM * DIM;
  f16* woh = wvh + (size_t)DIM * DIM;
  f16* Qp  = woh + (size_t)DIM * DIM;   // S*DIM
  f16* Kp  = Qp + (size_t)S_LEN * DIM;
  f16* Vt  = Kp + (size_t)S_LEN * DIM;  // DIM*S (transposed V proj)
  f16* IDn = qh;                        // S*S (8MB over qh+kh)
  f16* Ct  = vh;                        // S*DIM

  const int nqkv = S_LEN * DIM, nw = DIM * DIM;
  dim3 b256(256);
  cvt_f32_f16<<<nqkv / 1024, b256, 0, stream>>>(q, qh, nqkv / 4);
  cvt_f32_f16<<<nqkv / 1024, b256, 0, stream>>>(k, kh, nqkv / 4);
  cvt_f32_f16<<<nqkv / 1024, b256, 0, stream>>>(v, vh, nqkv / 4);
  cvt_f32_f16<<<nw / 1024, b256, 0, stream>>>(Wq, wqh, nw / 4);
  cvt_f32_f16<<<nw / 1024, b256, 0, stream>>>(Wk, wkh, nw / 4);
  cvt_f32_f16<<<nw / 1024, b256, 0, stream>>>(Wv, wvh, nw / 4);
  cvt_f32_f16<<<nw / 1024, b256, 0, stream>>>(Wo, woh, nw / 4);

  dim3 gg(DIM / 128, S_LEN / 128);
  gemm_xwt<0><<<gg, b256, 0, stream>>>(qh, wqh, bq, Qp, nullptr, S_LEN, DIM, DIM);
  gemm_xwt<0><<<gg, b256, 0, stream>>>(kh, wkh, bk, Kp, nullptr, S_LEN, DIM, DIM);
  gemm_xwt<1><<<gg, b256, 0, stream>>>(vh, wvh, bv, Vt, nullptr, S_LEN, DIM, DIM);

  attn_denom<<<dim3(S_LEN / 64, S_LEN / 64), b256, 0, stream>>>(Qp, Kp, IDn);
  attn_ctx<<<dim3(S_LEN / 64, NH), b256, 0, stream>>>(Qp, Kp, Vt, IDn, Ct);

  gemm_xwt<2><<<gg, b256, 0, stream>>>(Ct, woh, bo, nullptr, out, S_LEN, DIM, DIM);
}